// Round 32
// baseline (43.093 us; speedup 1.0000x reference)
//
#include <hip/hip_runtime.h>

// SSIM loss, 7x7 window, VALID, (64,1,512,512) fp32.
// R32 = R28 + tap-prefetch one iteration ahead, at ZERO marginal VALU:
// phase r computes from the 4 ds_read_b128 results ISSUED LAST PHASE
// (alternate f4 set, static parity naming); after staging row r+1 it
// issues row r+1's tap reads, whose lgkmcnt wait lands at the NEXT
// phase's start (~400cy slack vs ~120-160cy DS read->use latency).
// R18's version of this cost +35% VALU (f16 tap-set plumbing); here the
// only cost is +16 VGPR (76->~92, far under the 128 step; grid caps
// residency at 2 waves/SIMD anyway).
// Keeps R28: 2 cols/lane, shared-tap b128, incremental col B, pk-f32,
// SH=64, dual-slot LDS, depth-2 parity prefetch, barrier-free strips.

constexpr int B  = 64;
constexpr int H  = 512, W = 512;
constexpr int OH = H - 6, OW = W - 6;     // 506
constexpr int SH = 64;                    // output rows per block
// wave: 128 cols (2/lane); block: 4 waves = 512 cols; grid (1, 8, 64)

typedef float f2 __attribute__((ext_vector_type(2)));
typedef float f4 __attribute__((ext_vector_type(4)));

__global__ __launch_bounds__(256)
void ssim_main(const float* __restrict__ X, const float* __restrict__ Y,
               const float* __restrict__ DR, float* __restrict__ partials)
{
    const int tid  = threadIdx.x;
    const int wid  = tid >> 6;
    const int lane = tid & 63;
    const int c0   = wid * 128;             // block spans cols 0..511 (gx=1)
    const int gc   = c0 + 2 * lane;         // col A (even)
    const int r0   = blockIdx.y * SH;
    const int b    = blockIdx.z;

    const int out_rows = min(SH, OH - r0);
    const int rows_in  = out_rows + 6;       // 70, or 64 on last strip (even)

    const float d  = DR[b];
    const float C1 = (0.01f * d) * (0.01f * d);
    const float C2 = (0.03f * d) * (0.03f * d);
    const float c1s = 2401.0f * C1;          // 49^2 * C1
    const float c2s = 2352.0f * C2;          // 48*49 * C2

    const float* __restrict__ Xb = X + (size_t)b * H * W;
    const float* __restrict__ Yb = Y + (size_t)b * H * W;

    unsigned off  = (unsigned)(r0 * W + gc);
    unsigned hoff = (unsigned)(r0 * W + min(c0 + 128 + 2 * lane, W - 2));

    const bool vA = gc < OW;
    const bool vB = gc + 1 < OW;
    const bool is_halo = lane < 3;           // halo cols c0+128 .. c0+133

    // wave-private dual slots: 128 owned + 6 halo f2 entries ({x,y} per col)
    __shared__ __align__(16) f2 rb[4][2][136];

    // per-col state: P=(sx,sy) packed; ss=S(xx+yy); xy=Sxy. 7-row histories.
    f2 bPA[7], bPB[7];
    float bsA[7], bsB[7], bwA[7], bwB[7];
    f2 PA = {0.f,0.f}, PB = {0.f,0.f};
    float ssA = 0.f, ssB = 0.f, xyA = 0.f, xyB = 0.f;
#pragma unroll
    for (int i = 0; i < 7; ++i) {
        bPA[i]=PA; bPB[i]=PB; bsA[i]=0.f; bsB[i]=0.f; bwA[i]=0.f; bwB[i]=0.f;
    }

    float acc = 0.f;

    // parity prefetch (x,y col-pairs); pre1 = odd rows, pre0 = even rows
    f2 px0, py0, px1, py1;
    f2 phx0={0.f,0.f}, phy0={0.f,0.f}, phx1={0.f,0.f}, phy1={0.f,0.f};

    // double-buffered tap sets: qa* holds even rows' taps, qb* odd rows'
    f4 qa0, qa1, qa2, qa3, qb0, qb1, qb2, qb3;

    // ---- prologue: row0 -> slot0 (+taps into qa); row1 -> pre1; row2 -> pre0
    {
        const f2 x0 = *(const f2*)(Xb + off);
        const f2 y0 = *(const f2*)(Yb + off);
        f2 hx0={0.f,0.f}, hy0={0.f,0.f};
        if (is_halo) { hx0 = *(const f2*)(Xb + hoff); hy0 = *(const f2*)(Yb + hoff); }
        off += W; hoff += W;
        px1 = *(const f2*)(Xb + off); py1 = *(const f2*)(Yb + off);
        if (is_halo) { phx1 = *(const f2*)(Xb + hoff); phy1 = *(const f2*)(Yb + hoff); }
        off += W; hoff += W;
        px0 = *(const f2*)(Xb + off); py0 = *(const f2*)(Yb + off);
        if (is_halo) { phx0 = *(const f2*)(Xb + hoff); phy0 = *(const f2*)(Yb + hoff); }
        off += W; hoff += W;

        f2* s0 = rb[wid][0];
        *(f4*)&s0[2*lane] = (f4){x0.x, y0.x, x0.y, y0.y};
        if (is_halo) *(f4*)&s0[128 + 2*lane] = (f4){hx0.x, hy0.x, hx0.y, hy0.y};
        qa0 = *(const f4*)&s0[2*lane + 0];
        qa1 = *(const f4*)&s0[2*lane + 2];
        qa2 = *(const f4*)&s0[2*lane + 4];
        qa3 = *(const f4*)&s0[2*lane + 6];
    }

    for (int rr = 0; rr < 70; rr += 14) {
#pragma unroll
        for (int p = 0; p < 14; ++p) {
            const int r = rr + p;              // r%7 == p%7, r&1 == p&1
            if (r < rows_in) {                 // block-uniform
                f2* const wslot = rb[wid][(p & 1) ^ 1];  // row r+1 dest
                f2& px = (p & 1) ? px0 : px1;            // pair(r+1)
                f2& py = (p & 1) ? py0 : py1;
                f2& phx = (p & 1) ? phx0 : phx1;
                f2& phy = (p & 1) ? phy0 : phy1;
                // current taps (row r, read LAST phase); next set to fill
                f4& tc0 = (p & 1) ? qb0 : qa0;
                f4& tc1 = (p & 1) ? qb1 : qa1;
                f4& tc2 = (p & 1) ? qb2 : qa2;
                f4& tc3 = (p & 1) ? qb3 : qa3;
                f4& tn0 = (p & 1) ? qa0 : qb0;
                f4& tn1 = (p & 1) ? qa1 : qb1;
                f4& tn2 = (p & 1) ? qa2 : qb2;
                f4& tn3 = (p & 1) ? qa3 : qb3;

                // 1) stage row r+1; 2) prefetch row r+3; 3) issue row r+1's
                //    tap reads into the alternate set (consumed next phase)
                if (r + 1 < rows_in) {
                    *(f4*)&wslot[2*lane] = (f4){px.x, py.x, px.y, py.y};
                    if (is_halo)
                        *(f4*)&wslot[128 + 2*lane] = (f4){phx.x, phy.x, phx.y, phy.y};
                    if (r + 3 < rows_in) {
                        px = *(const f2*)(Xb + off);
                        py = *(const f2*)(Yb + off);
                        if (is_halo) { phx = *(const f2*)(Xb + hoff);
                                       phy = *(const f2*)(Yb + hoff); }
                        off += W; hoff += W;
                    }
                    tn0 = *(const f4*)&wslot[2*lane + 0];
                    tn1 = *(const f4*)&wslot[2*lane + 2];
                    tn2 = *(const f4*)&wslot[2*lane + 4];
                    tn3 = *(const f4*)&wslot[2*lane + 6];
                }

                // 4) compute row r from taps read LAST phase (no DS wait)
                const f4 q0 = tc0, q1 = tc1, q2 = tc2, q3 = tc3;
                const f2 t0={q0.x,q0.y}, t1={q0.z,q0.w},
                         t2={q1.x,q1.y}, t3={q1.z,q1.w},
                         t4={q2.x,q2.y}, t5={q2.z,q2.w},
                         t6={q3.x,q3.y}, t7={q3.z,q3.w};

                const f2 s2A = ((t0+t1)+(t2+t3)) + ((t4+t5)+t6);
                const f2 s2B = (s2A - t0) + t7;
                const f2 tsq0 = t0*t0, tsq7 = t7*t7;
                f2 q2A = tsq0;
                q2A = __builtin_elementwise_fma(t1,t1,q2A);
                q2A = __builtin_elementwise_fma(t2,t2,q2A);
                q2A = __builtin_elementwise_fma(t3,t3,q2A);
                q2A = __builtin_elementwise_fma(t4,t4,q2A);
                q2A = __builtin_elementwise_fma(t5,t5,q2A);
                q2A = __builtin_elementwise_fma(t6,t6,q2A);
                const f2 q2B = (q2A - tsq0) + tsq7;
                const float hsA = q2A.x + q2A.y;
                const float hsB = q2B.x + q2B.y;
                const float t0xy = t0.x * t0.y;
                float hxyA = t0xy;
                hxyA = fmaf(t1.x,t1.y,hxyA); hxyA = fmaf(t2.x,t2.y,hxyA);
                hxyA = fmaf(t3.x,t3.y,hxyA); hxyA = fmaf(t4.x,t4.y,hxyA);
                hxyA = fmaf(t5.x,t5.y,hxyA); hxyA = fmaf(t6.x,t6.y,hxyA);
                const float hxyB = fmaf(t7.x, t7.y, hxyA - t0xy);

                // vertical running 7-row window (slot p%7 holds row r-7)
                constexpr int s7[14] = {0,1,2,3,4,5,6,0,1,2,3,4,5,6};
                const int sp = s7[p];
                PA  += s2A  - bPA[sp]; bPA[sp] = s2A;
                ssA += hsA  - bsA[sp]; bsA[sp] = hsA;
                xyA += hxyA - bwA[sp]; bwA[sp] = hxyA;
                PB  += s2B  - bPB[sp]; bPB[sp] = s2B;
                ssB += hsB  - bsB[sp]; bsB[sp] = hsB;
                xyB += hxyB - bwB[sp]; bwB[sp] = hxyB;

                if (r >= 6) {
                    // S = (2 SxSy + c1s)(2(49 Sxy - SxSy) + c2s)
                    //   / (Sx^2+Sy^2+c1s)(49 ss - Sx^2 - Sy^2 + c2s)
                    {   const float p1 = PA.x * PA.y;
                        const float u1 = fmaf(2.f, p1, c1s);
                        const float qv = fmaf(49.f, xyA, -p1);
                        const float u2 = fmaf(2.f, qv, c2s);
                        const float n2 = fmaf(PA.y, PA.y, PA.x * PA.x);
                        const float d1 = n2 + c1s;
                        const float d2 = fmaf(49.f, ssA, c2s) - n2;
                        const float den = d1 * d2;
                        float rc = __builtin_amdgcn_rcpf(den);
                        rc = rc * (2.f - den * rc);
                        acc += vA ? (u1 * u2) * rc : 0.f;
                    }
                    {   const float p1 = PB.x * PB.y;
                        const float u1 = fmaf(2.f, p1, c1s);
                        const float qv = fmaf(49.f, xyB, -p1);
                        const float u2 = fmaf(2.f, qv, c2s);
                        const float n2 = fmaf(PB.y, PB.y, PB.x * PB.x);
                        const float d1 = n2 + c1s;
                        const float d2 = fmaf(49.f, ssB, c2s) - n2;
                        const float den = d1 * d2;
                        float rc = __builtin_amdgcn_rcpf(den);
                        rc = rc * (2.f - den * rc);
                        acc += vB ? (u1 * u2) * rc : 0.f;
                    }
                }
            }
        }
    }

    // block reduction: wave shfl, then cross-wave via LDS (single barrier)
    float s = acc;
#pragma unroll
    for (int o = 32; o; o >>= 1) s += __shfl_down(s, o, 64);
    __shared__ float wsum[4];
    if (lane == 0) wsum[wid] = s;
    __syncthreads();
    if (tid == 0) {
        const int bid = blockIdx.z * gridDim.y + blockIdx.y;
        partials[bid] = wsum[0] + wsum[1] + wsum[2] + wsum[3];
    }
}

__global__ __launch_bounds__(256)
void ssim_final(const float* __restrict__ partials, int n,
                float* __restrict__ out, float inv_count)
{
    const int tid = threadIdx.x;
    float s = 0.f;
    for (int i = tid; i < n; i += 256) s += partials[i];
#pragma unroll
    for (int o = 32; o; o >>= 1) s += __shfl_down(s, o, 64);
    __shared__ float wsum[4];
    if ((tid & 63) == 0) wsum[tid >> 6] = s;
    __syncthreads();
    if (tid == 0) out[0] = 1.0f - (wsum[0] + wsum[1] + wsum[2] + wsum[3]) * inv_count;
}

extern "C" void kernel_launch(void* const* d_in, const int* in_sizes, int n_in,
                              void* d_out, int out_size, void* d_ws, size_t ws_size,
                              hipStream_t stream)
{
    const float* X  = (const float*)d_in[0];
    const float* Y  = (const float*)d_in[1];
    const float* DR = (const float*)d_in[2];
    float* out      = (float*)d_out;
    float* partials = (float*)d_ws;

    const int gy = (OH + SH - 1) / SH;   // 8
    dim3 grid(1, gy, B);                 // 512 blocks, every partial slot written
    ssim_main<<<grid, 256, 0, stream>>>(X, Y, DR, partials);

    const int n = gy * B;                // 512
    const float inv_count = 1.0f / (float)((long)B * OH * OW);
    ssim_final<<<1, 256, 0, stream>>>(partials, n, out, inv_count);
}

// Round 33
// 42.730 us; speedup vs baseline: 1.0085x; 1.0085x over previous
//
#include <hip/hip_runtime.h>

// SSIM loss, 7x7 window, VALID, (64,1,512,512) fp32.
// FINAL (R28 verbatim, champion 42.7-42.9us): 2 cols/lane, shared-tap
// b128 reads, incremental col B, pk-f32 channel math, SH=64, read-early
// dual-slot LDS, depth-2 parity prefetch, barrier-free wave strips.
//
// Plateau record: VALU floor ~25us (143k wave-iters x 428cy / 1024 SIMDs,
// = measured VALUBusy*dur), memory floor ~21us (134MB @ 6.3TB/s). The
// ~18us above the VALU floor is DS/issue dependency latency at 2 waves/
// SIMD; 7 structural attempts (tap-dbuf R18, read-early R19, b128 batch
// R21, occupancy R23, dual-strip R29, fused-reduce R30, tap-prefetch R32)
// were all neutral-to-negative. Ladder: 74.8 (naive-tile) -> 50.5 (no
// VGPR pin) -> 46.9 (op-diet) -> 44.8 (pk-f32) -> 42.9 (2-col + SH=64).

constexpr int B  = 64;
constexpr int H  = 512, W = 512;
constexpr int OH = H - 6, OW = W - 6;     // 506
constexpr int SH = 64;                    // output rows per block
// wave: 128 cols (2/lane); block: 4 waves = 512 cols; grid (1, 8, 64)

typedef float f2 __attribute__((ext_vector_type(2)));
typedef float f4 __attribute__((ext_vector_type(4)));

__global__ __launch_bounds__(256)
void ssim_main(const float* __restrict__ X, const float* __restrict__ Y,
               const float* __restrict__ DR, float* __restrict__ partials)
{
    const int tid  = threadIdx.x;
    const int wid  = tid >> 6;
    const int lane = tid & 63;
    const int c0   = wid * 128;             // block spans cols 0..511 (gx=1)
    const int gc   = c0 + 2 * lane;         // col A (even)
    const int r0   = blockIdx.y * SH;
    const int b    = blockIdx.z;

    const int out_rows = min(SH, OH - r0);
    const int rows_in  = out_rows + 6;       // 70, or 64 on last strip (even)

    const float d  = DR[b];
    const float C1 = (0.01f * d) * (0.01f * d);
    const float C2 = (0.03f * d) * (0.03f * d);
    const float c1s = 2401.0f * C1;          // 49^2 * C1
    const float c2s = 2352.0f * C2;          // 48*49 * C2

    const float* __restrict__ Xb = X + (size_t)b * H * W;
    const float* __restrict__ Yb = Y + (size_t)b * H * W;

    unsigned off  = (unsigned)(r0 * W + gc);
    unsigned hoff = (unsigned)(r0 * W + min(c0 + 128 + 2 * lane, W - 2));

    const bool vA = gc < OW;
    const bool vB = gc + 1 < OW;
    const bool is_halo = lane < 3;           // halo cols c0+128 .. c0+133

    // wave-private dual slots: 128 owned + 6 halo f2 entries ({x,y} per col)
    __shared__ __align__(16) f2 rb[4][2][136];

    // per-col state: P=(sx,sy) packed; ss=S(xx+yy); xy=Sxy. 7-row histories.
    f2 bPA[7], bPB[7];
    float bsA[7], bsB[7], bwA[7], bwB[7];
    f2 PA = {0.f,0.f}, PB = {0.f,0.f};
    float ssA = 0.f, ssB = 0.f, xyA = 0.f, xyB = 0.f;
#pragma unroll
    for (int i = 0; i < 7; ++i) {
        bPA[i]=PA; bPB[i]=PB; bsA[i]=0.f; bsB[i]=0.f; bwA[i]=0.f; bwB[i]=0.f;
    }

    float acc = 0.f;

    // parity prefetch (x,y col-pairs); pre1 = odd rows, pre0 = even rows
    f2 px0, py0, px1, py1;
    f2 phx0={0.f,0.f}, phy0={0.f,0.f}, phx1={0.f,0.f}, phy1={0.f,0.f};

    // ---- prologue: row0 -> slot0; row1 -> pre1; row2 -> pre0 ----
    {
        const f2 x0 = *(const f2*)(Xb + off);
        const f2 y0 = *(const f2*)(Yb + off);
        f2 hx0={0.f,0.f}, hy0={0.f,0.f};
        if (is_halo) { hx0 = *(const f2*)(Xb + hoff); hy0 = *(const f2*)(Yb + hoff); }
        off += W; hoff += W;
        px1 = *(const f2*)(Xb + off); py1 = *(const f2*)(Yb + off);
        if (is_halo) { phx1 = *(const f2*)(Xb + hoff); phy1 = *(const f2*)(Yb + hoff); }
        off += W; hoff += W;
        px0 = *(const f2*)(Xb + off); py0 = *(const f2*)(Yb + off);
        if (is_halo) { phx0 = *(const f2*)(Xb + hoff); phy0 = *(const f2*)(Yb + hoff); }
        off += W; hoff += W;

        f2* s0 = rb[wid][0];
        *(f4*)&s0[2*lane] = (f4){x0.x, y0.x, x0.y, y0.y};
        if (is_halo) *(f4*)&s0[128 + 2*lane] = (f4){hx0.x, hy0.x, hx0.y, hy0.y};
    }

    for (int rr = 0; rr < 70; rr += 14) {
#pragma unroll
        for (int p = 0; p < 14; ++p) {
            const int r = rr + p;              // r%7 == p%7, r&1 == p&1
            if (r < rows_in) {                 // block-uniform
                f2* const rslot = rb[wid][p & 1];        // row r (staged)
                f2* const wslot = rb[wid][(p & 1) ^ 1];  // row r+1 dest
                f2& px = (p & 1) ? px0 : px1;            // pair(r+1)
                f2& py = (p & 1) ? py0 : py1;
                f2& phx = (p & 1) ? phx0 : phx1;
                f2& phy = (p & 1) ? phy0 : phy1;

                // 1) tap reads: 4x ds_read_b128 -> cols gc..gc+7
                const f4 q0 = *(const f4*)&rslot[2*lane + 0];
                const f4 q1 = *(const f4*)&rslot[2*lane + 2];
                const f4 q2 = *(const f4*)&rslot[2*lane + 4];
                const f4 q3 = *(const f4*)&rslot[2*lane + 6];

                // 2) stage row r+1 (one b128 + halo); 3) prefetch row r+3
                if (r + 1 < rows_in) {
                    *(f4*)&wslot[2*lane] = (f4){px.x, py.x, px.y, py.y};
                    if (is_halo)
                        *(f4*)&wslot[128 + 2*lane] = (f4){phx.x, phy.x, phx.y, phy.y};
                    if (r + 3 < rows_in) {
                        px = *(const f2*)(Xb + off);
                        py = *(const f2*)(Yb + off);
                        if (is_halo) { phx = *(const f2*)(Xb + hoff);
                                       phy = *(const f2*)(Yb + hoff); }
                        off += W; hoff += W;
                    }
                }

                // 4) compute cols A (taps 0-6) and B (incremental, taps 1-7)
                const f2 t0={q0.x,q0.y}, t1={q0.z,q0.w},
                         t2={q1.x,q1.y}, t3={q1.z,q1.w},
                         t4={q2.x,q2.y}, t5={q2.z,q2.w},
                         t6={q3.x,q3.y}, t7={q3.z,q3.w};

                const f2 s2A = ((t0+t1)+(t2+t3)) + ((t4+t5)+t6);
                const f2 s2B = (s2A - t0) + t7;
                const f2 tsq0 = t0*t0, tsq7 = t7*t7;
                f2 q2A = tsq0;
                q2A = __builtin_elementwise_fma(t1,t1,q2A);
                q2A = __builtin_elementwise_fma(t2,t2,q2A);
                q2A = __builtin_elementwise_fma(t3,t3,q2A);
                q2A = __builtin_elementwise_fma(t4,t4,q2A);
                q2A = __builtin_elementwise_fma(t5,t5,q2A);
                q2A = __builtin_elementwise_fma(t6,t6,q2A);
                const f2 q2B = (q2A - tsq0) + tsq7;
                const float hsA = q2A.x + q2A.y;
                const float hsB = q2B.x + q2B.y;
                const float t0xy = t0.x * t0.y;
                float hxyA = t0xy;
                hxyA = fmaf(t1.x,t1.y,hxyA); hxyA = fmaf(t2.x,t2.y,hxyA);
                hxyA = fmaf(t3.x,t3.y,hxyA); hxyA = fmaf(t4.x,t4.y,hxyA);
                hxyA = fmaf(t5.x,t5.y,hxyA); hxyA = fmaf(t6.x,t6.y,hxyA);
                const float hxyB = fmaf(t7.x, t7.y, hxyA - t0xy);

                // vertical running 7-row window (slot p%7 holds row r-7)
                constexpr int s7[14] = {0,1,2,3,4,5,6,0,1,2,3,4,5,6};
                const int sp = s7[p];
                PA  += s2A  - bPA[sp]; bPA[sp] = s2A;
                ssA += hsA  - bsA[sp]; bsA[sp] = hsA;
                xyA += hxyA - bwA[sp]; bwA[sp] = hxyA;
                PB  += s2B  - bPB[sp]; bPB[sp] = s2B;
                ssB += hsB  - bsB[sp]; bsB[sp] = hsB;
                xyB += hxyB - bwB[sp]; bwB[sp] = hxyB;

                if (r >= 6) {
                    // S = (2 SxSy + c1s)(2(49 Sxy - SxSy) + c2s)
                    //   / (Sx^2+Sy^2+c1s)(49 ss - Sx^2 - Sy^2 + c2s)
                    {   const float p1 = PA.x * PA.y;
                        const float u1 = fmaf(2.f, p1, c1s);
                        const float qv = fmaf(49.f, xyA, -p1);
                        const float u2 = fmaf(2.f, qv, c2s);
                        const float n2 = fmaf(PA.y, PA.y, PA.x * PA.x);
                        const float d1 = n2 + c1s;
                        const float d2 = fmaf(49.f, ssA, c2s) - n2;
                        const float den = d1 * d2;
                        float rc = __builtin_amdgcn_rcpf(den);
                        rc = rc * (2.f - den * rc);
                        acc += vA ? (u1 * u2) * rc : 0.f;
                    }
                    {   const float p1 = PB.x * PB.y;
                        const float u1 = fmaf(2.f, p1, c1s);
                        const float qv = fmaf(49.f, xyB, -p1);
                        const float u2 = fmaf(2.f, qv, c2s);
                        const float n2 = fmaf(PB.y, PB.y, PB.x * PB.x);
                        const float d1 = n2 + c1s;
                        const float d2 = fmaf(49.f, ssB, c2s) - n2;
                        const float den = d1 * d2;
                        float rc = __builtin_amdgcn_rcpf(den);
                        rc = rc * (2.f - den * rc);
                        acc += vB ? (u1 * u2) * rc : 0.f;
                    }
                }
            }
        }
    }

    // block reduction: wave shfl, then cross-wave via LDS (single barrier)
    float s = acc;
#pragma unroll
    for (int o = 32; o; o >>= 1) s += __shfl_down(s, o, 64);
    __shared__ float wsum[4];
    if (lane == 0) wsum[wid] = s;
    __syncthreads();
    if (tid == 0) {
        const int bid = blockIdx.z * gridDim.y + blockIdx.y;
        partials[bid] = wsum[0] + wsum[1] + wsum[2] + wsum[3];
    }
}

__global__ __launch_bounds__(256)
void ssim_final(const float* __restrict__ partials, int n,
                float* __restrict__ out, float inv_count)
{
    const int tid = threadIdx.x;
    float s = 0.f;
    for (int i = tid; i < n; i += 256) s += partials[i];
#pragma unroll
    for (int o = 32; o; o >>= 1) s += __shfl_down(s, o, 64);
    __shared__ float wsum[4];
    if ((tid & 63) == 0) wsum[tid >> 6] = s;
    __syncthreads();
    if (tid == 0) out[0] = 1.0f - (wsum[0] + wsum[1] + wsum[2] + wsum[3]) * inv_count;
}

extern "C" void kernel_launch(void* const* d_in, const int* in_sizes, int n_in,
                              void* d_out, int out_size, void* d_ws, size_t ws_size,
                              hipStream_t stream)
{
    const float* X  = (const float*)d_in[0];
    const float* Y  = (const float*)d_in[1];
    const float* DR = (const float*)d_in[2];
    float* out      = (float*)d_out;
    float* partials = (float*)d_ws;

    const int gy = (OH + SH - 1) / SH;   // 8
    dim3 grid(1, gy, B);                 // 512 blocks, every partial slot written
    ssim_main<<<grid, 256, 0, stream>>>(X, Y, DR, partials);

    const int n = gy * B;                // 512
    const float inv_count = 1.0f / (float)((long)B * OH * OW);
    ssim_final<<<1, 256, 0, stream>>>(partials, n, out, inv_count);
}